// Round 2
// baseline (2784.216 us; speedup 1.0000x reference)
//
#include <hip/hip_runtime.h>
#include <hip/hip_bf16.h>

// AttentiveFuturecaster: fused GRU-encoder + attentive GRU-decoder + FC head.
// Round 2: inputs/outputs are FP32 (per reference dtypes). MFMA runs on bf16
// with split-bf16 (hi+lo) A-operands and fp32-carried hidden state in LDS, so
// recurrence error does not accumulate. Weights are pre-converted fp32->bf16
// into d_ws by a prologue kernel (single L2-resident bf16 copy).
// ws layout: [0, 128MB): hs bf16 [B,T,H]; then 1MB bf16 weight blob.

#define B_    2048
#define T_    128
#define F_    64
#define H_    256
#define OUT_  32
#define BT_   16
#define NTH_  512
#define NB_   (B_ / BT_)
#define HSTR_ 264   // bf16 h-tile LDS row stride
#define FSTR_ 260   // fp32 h-tile LDS row stride
#define XSTR_ 72    // bf16 x-tile LDS row stride
#define SSTR_ 260   // fp32 scratch row stride (softmax w / fc1 out)

// bf16 weight blob element offsets inside ws (after hs)
#define W_EIH_  0
#define W_EHH_  (W_EIH_ + 3 * H_ * F_)     // 49152
#define W_DHH_  (W_EHH_ + 3 * H_ * H_)     // 245760
#define W_F1_   (W_DHH_ + 3 * H_ * H_)     // 442368
#define W_TOT_  (W_F1_ + H_ * H_)          // 507904

typedef __attribute__((ext_vector_type(8))) short bf16x8;
typedef __attribute__((ext_vector_type(4))) float f32x4;

__device__ __forceinline__ f32x4 mfma16(bf16x8 a, bf16x8 b, f32x4 c) {
  return __builtin_amdgcn_mfma_f32_16x16x32_bf16(a, b, c, 0, 0, 0);
}
__device__ __forceinline__ float sigm_(float x) { return 1.0f / (1.0f + __expf(-x)); }
__device__ __forceinline__ float tanh_(float x) {
  x = fminf(15.0f, fmaxf(-15.0f, x));
  float e = __expf(2.0f * x);
  return (e - 1.0f) / (e + 1.0f);
}

__global__ __launch_bounds__(256) void af_convert_weights(
    const float* __restrict__ eWih, const float* __restrict__ eWhh,
    const float* __restrict__ dWhh, const float* __restrict__ f1W,
    __hip_bfloat16* __restrict__ wb) {
  for (int i = blockIdx.x * blockDim.x + threadIdx.x; i < W_TOT_;
       i += gridDim.x * blockDim.x) {
    float v;
    if (i < W_EHH_)      v = eWih[i - W_EIH_];
    else if (i < W_DHH_) v = eWhh[i - W_EHH_];
    else if (i < W_F1_)  v = dWhh[i - W_DHH_];
    else                 v = f1W[i - W_F1_];
    wb[i] = __float2bfloat16(v);
  }
}

__global__ __launch_bounds__(NTH_) void af_fused_kernel(
    const float* __restrict__ x,
    const float* __restrict__ h0,
    const float* __restrict__ ebih,
    const float* __restrict__ ebhh,
    const float* __restrict__ dWih,
    const float* __restrict__ dbih,
    const float* __restrict__ dbhh,
    const float* __restrict__ aWq,
    const float* __restrict__ abq,
    const float* __restrict__ f1b,
    const float* __restrict__ f2W,
    const float* __restrict__ f2b,
    const __hip_bfloat16* __restrict__ eWihB,
    const __hip_bfloat16* __restrict__ eWhhB,
    const __hip_bfloat16* __restrict__ dWhhB,
    const __hip_bfloat16* __restrict__ f1WB,
    __hip_bfloat16* __restrict__ hs,     // [B,T,H] bf16 (workspace)
    float* __restrict__ dout)            // [B,OUT] fp32
{
  __shared__ __hip_bfloat16 sh_h[2][BT_ * HSTR_];   // h hi (bf16)
  __shared__ __hip_bfloat16 sh_l[2][BT_ * HSTR_];   // h lo (bf16 residual)
  __shared__ float          s_hf[2][BT_ * FSTR_];   // h fp32 (carried state)
  __shared__ __hip_bfloat16 sh_x[2][BT_ * XSTR_];   // x hi
  __shared__ __hip_bfloat16 sh_xl[2][BT_ * XSTR_];  // x lo
  __shared__ float s_A[BT_ * T_], s_C[BT_ * T_];    // rank-1 attention tables
  __shared__ float s_ebr[H_], s_ebz[H_], s_ebin[H_], s_ebhn[H_];
  __shared__ float s_dbr[H_], s_dbz[H_], s_dbin[H_], s_dbhn[H_];
  __shared__ float s_dwih[3 * H_];
  __shared__ float s_wq[H_], s_bq[H_], s_f1b[H_], s_f2w[H_];
  __shared__ float s_f2b;
  __shared__ float s_prev[BT_];
  __shared__ float s_scr[BT_ * SSTR_];  // softmax w (cols 0..127) / fc1 out (cols 0..255)

  const int tid  = threadIdx.x;
  const int b0   = blockIdx.x * BT_;
  const int lane = tid & 63;
  const int wid  = tid >> 6;     // 0..7
  const int quad = lane >> 4;    // 0..3
  const int l16  = lane & 15;    // 0..15
  const int mg   = tid >> 5;     // 0..15: batch row for 32-thread-group phases
  const int cg   = tid & 31;     // 0..31: position within group

  // ---------------- prologue: constants + h0 + x(t=0) into LDS ----------------
  for (int g = tid; g < H_; g += NTH_) {
    s_ebr[g]  = ebih[g]          + ebhh[g];
    s_ebz[g]  = ebih[H_ + g]     + ebhh[H_ + g];
    s_ebin[g] = ebih[2 * H_ + g];
    s_ebhn[g] = ebhh[2 * H_ + g];
    s_dbr[g]  = dbih[g]          + dbhh[g];
    s_dbz[g]  = dbih[H_ + g]     + dbhh[H_ + g];
    s_dbin[g] = dbih[2 * H_ + g];
    s_dbhn[g] = dbhh[2 * H_ + g];
    s_wq[g]   = aWq[g];
    s_bq[g]   = abq[g];
    s_f1b[g]  = f1b[g];
    s_f2w[g]  = f2W[g];
  }
  for (int g = tid; g < 3 * H_; g += NTH_) s_dwih[g] = dWih[g];
  if (tid == 0) s_f2b = f2b[0];

  {
    const float* hp = h0 + (size_t)(b0 + mg) * H_ + cg * 8;
    float4 v0 = *(const float4*)(hp);
    float4 v1 = *(const float4*)(hp + 4);
    float vv[8] = {v0.x, v0.y, v0.z, v0.w, v1.x, v1.y, v1.z, v1.w};
#pragma unroll
    for (int j = 0; j < 8; ++j) {
      float v = vv[j];
      s_hf[0][mg * FSTR_ + cg * 8 + j] = v;
      __hip_bfloat16 hi = __float2bfloat16(v);
      sh_h[0][mg * HSTR_ + cg * 8 + j] = hi;
      sh_l[0][mg * HSTR_ + cg * 8 + j] = __float2bfloat16(v - __bfloat162float(hi));
    }
    float2 xv = *(const float2*)(x + ((size_t)(b0 + mg) * T_) * F_ + cg * 2);
    __hip_bfloat16 xh0 = __float2bfloat16(xv.x);
    __hip_bfloat16 xh1 = __float2bfloat16(xv.y);
    sh_x[0][mg * XSTR_ + cg * 2]      = xh0;
    sh_x[0][mg * XSTR_ + cg * 2 + 1]  = xh1;
    sh_xl[0][mg * XSTR_ + cg * 2]     = __float2bfloat16(xv.x - __bfloat162float(xh0));
    sh_xl[0][mg * XSTR_ + cg * 2 + 1] = __float2bfloat16(xv.y - __bfloat162float(xh1));
  }
  __syncthreads();

  // ============================ ENCODER: 128 GRU steps ============================
  int cur = 0;
  for (int t = 0; t < T_; ++t) {
    const int nxt = cur ^ 1;
    bf16x8 ah[8], al[8], ax[2], axl[2];
#pragma unroll
    for (int kk = 0; kk < 8; ++kk) {
      ah[kk] = *(const bf16x8*)&sh_h[cur][l16 * HSTR_ + kk * 32 + quad * 8];
      al[kk] = *(const bf16x8*)&sh_l[cur][l16 * HSTR_ + kk * 32 + quad * 8];
    }
#pragma unroll
    for (int kk = 0; kk < 2; ++kk) {
      ax[kk]  = *(const bf16x8*)&sh_x[cur][l16 * XSTR_ + kk * 32 + quad * 8];
      axl[kk] = *(const bf16x8*)&sh_xl[cur][l16 * XSTR_ + kk * 32 + quad * 8];
    }

#pragma unroll
    for (int s2 = 0; s2 < 2; ++s2) {
      const int c = 2 * wid + s2;       // h-column block 0..15
      const int g = 16 * c + l16;       // gate column 0..255
      const __hip_bfloat16* pr = eWhhB + (size_t)g * H_ + quad * 8;
      const __hip_bfloat16* pz = eWhhB + (size_t)(H_ + g) * H_ + quad * 8;
      const __hip_bfloat16* pn = eWhhB + (size_t)(2 * H_ + g) * H_ + quad * 8;
      f32x4 ar = {0.f, 0.f, 0.f, 0.f}, az = ar, ani = ar, anh = ar;
#pragma unroll
      for (int kk = 0; kk < 8; ++kk) {
        bf16x8 br = *(const bf16x8*)(pr + kk * 32);
        bf16x8 bz = *(const bf16x8*)(pz + kk * 32);
        bf16x8 bn = *(const bf16x8*)(pn + kk * 32);
        ar  = mfma16(al[kk], br, ar);  ar  = mfma16(ah[kk], br, ar);
        az  = mfma16(al[kk], bz, az);  az  = mfma16(ah[kk], bz, az);
        anh = mfma16(al[kk], bn, anh); anh = mfma16(ah[kk], bn, anh);
      }
      const __hip_bfloat16* qr = eWihB + (size_t)g * F_ + quad * 8;
      const __hip_bfloat16* qz = eWihB + (size_t)(H_ + g) * F_ + quad * 8;
      const __hip_bfloat16* qn = eWihB + (size_t)(2 * H_ + g) * F_ + quad * 8;
#pragma unroll
      for (int kk = 0; kk < 2; ++kk) {
        bf16x8 br = *(const bf16x8*)(qr + kk * 32);
        bf16x8 bz = *(const bf16x8*)(qz + kk * 32);
        bf16x8 bn = *(const bf16x8*)(qn + kk * 32);
        ar  = mfma16(axl[kk], br, ar);  ar  = mfma16(ax[kk], br, ar);
        az  = mfma16(axl[kk], bz, az);  az  = mfma16(ax[kk], bz, az);
        ani = mfma16(axl[kk], bn, ani); ani = mfma16(ax[kk], bn, ani);
      }
      const float br_ = s_ebr[g], bz_ = s_ebz[g], bin_ = s_ebin[g], bhn_ = s_ebhn[g];
#pragma unroll
      for (int i = 0; i < 4; ++i) {
        const int m = quad * 4 + i;     // D row = batch
        float r = sigm_(ar[i] + br_);
        float z = sigm_(az[i] + bz_);
        float n = tanh_(ani[i] + bin_ + r * (anh[i] + bhn_));
        float hold = s_hf[cur][m * FSTR_ + g];
        float hn = (1.0f - z) * n + z * hold;
        s_hf[nxt][m * FSTR_ + g] = hn;
        __hip_bfloat16 hi = __float2bfloat16(hn);
        sh_h[nxt][m * HSTR_ + g] = hi;
        sh_l[nxt][m * HSTR_ + g] = __float2bfloat16(hn - __bfloat162float(hi));
      }
    }
    __syncthreads();

    // output phase: hs store (bf16 hi), A/C dots (fp32), x prefetch (t+1)
    {
      uint4 hv = *(const uint4*)&sh_h[nxt][mg * HSTR_ + cg * 8];
      *(uint4*)&hs[((size_t)(b0 + mg) * T_ + t) * H_ + cg * 8] = hv;
      const float* hp = &s_hf[nxt][mg * FSTR_ + cg * 8];
      float pa = 0.f, pc = 0.f;
#pragma unroll
      for (int j = 0; j < 8; ++j) {
        float hvf = hp[j];
        pa += hvf * s_wq[cg * 8 + j];
        pc += hvf * s_bq[cg * 8 + j];
      }
#pragma unroll
      for (int off = 16; off >= 1; off >>= 1) {
        pa += __shfl_xor(pa, off, 64);
        pc += __shfl_xor(pc, off, 64);
      }
      if (cg == 0) {
        s_A[mg * T_ + t] = pa;
        s_C[mg * T_ + t] = pc;
      }
      if (t + 1 < T_) {
        float2 xv = *(const float2*)(x + ((size_t)(b0 + mg) * T_ + (t + 1)) * F_ + cg * 2);
        __hip_bfloat16 xh0 = __float2bfloat16(xv.x);
        __hip_bfloat16 xh1 = __float2bfloat16(xv.y);
        sh_x[nxt][mg * XSTR_ + cg * 2]      = xh0;
        sh_x[nxt][mg * XSTR_ + cg * 2 + 1]  = xh1;
        sh_xl[nxt][mg * XSTR_ + cg * 2]     = __float2bfloat16(xv.x - __bfloat162float(xh0));
        sh_xl[nxt][mg * XSTR_ + cg * 2 + 1] = __float2bfloat16(xv.y - __bfloat162float(xh1));
      }
    }
    __syncthreads();
    cur = nxt;
  }

  // ============================ DECODER: 32 steps ============================
  if (tid < BT_)
    s_prev[tid] = x[((size_t)(b0 + tid) * T_ + (T_ - 1)) * F_];
  __syncthreads();

  for (int s = 0; s < OUT_; ++s) {
    // P1: scores = (prev*A + C)*scale, softmax over T per batch row -> s_scr
    {
      float4 a4 = *(const float4*)(s_A + mg * T_ + cg * 4);
      float4 c4 = *(const float4*)(s_C + mg * T_ + cg * 4);
      const float pv = s_prev[mg];
      float sc0 = (pv * a4.x + c4.x) * 0.0625f;
      float sc1 = (pv * a4.y + c4.y) * 0.0625f;
      float sc2 = (pv * a4.z + c4.z) * 0.0625f;
      float sc3 = (pv * a4.w + c4.w) * 0.0625f;
      float mx = fmaxf(fmaxf(sc0, sc1), fmaxf(sc2, sc3));
#pragma unroll
      for (int off = 16; off >= 1; off >>= 1) mx = fmaxf(mx, __shfl_xor(mx, off, 64));
      float e0 = __expf(sc0 - mx), e1 = __expf(sc1 - mx);
      float e2 = __expf(sc2 - mx), e3 = __expf(sc3 - mx);
      float ss = e0 + e1 + e2 + e3;
#pragma unroll
      for (int off = 16; off >= 1; off >>= 1) ss += __shfl_xor(ss, off, 64);
      const float inv = 1.0f / ss;
      float4 wv = make_float4(e0 * inv, e1 * inv, e2 * inv, e3 * inv);
      *(float4*)&s_scr[mg * SSTR_ + cg * 4] = wv;
    }
    __syncthreads();

    // P2: ctx[m,h] = sum_t w[m,t] * hs[m,t,h]  (fp32 VALU, bf16 loads)
    {
      float acc[8] = {0.f, 0.f, 0.f, 0.f, 0.f, 0.f, 0.f, 0.f};
      const __hip_bfloat16* hp = hs + (size_t)(b0 + mg) * T_ * H_ + cg * 8;
      const float* wp = &s_scr[mg * SSTR_];
      for (int t = 0; t < T_; ++t) {
        uint4 hv = *(const uint4*)(hp + (size_t)t * H_);
        const float wt = wp[t];
        acc[0] = fmaf(wt, __uint_as_float(hv.x << 16),         acc[0]);
        acc[1] = fmaf(wt, __uint_as_float(hv.x & 0xFFFF0000u), acc[1]);
        acc[2] = fmaf(wt, __uint_as_float(hv.y << 16),         acc[2]);
        acc[3] = fmaf(wt, __uint_as_float(hv.y & 0xFFFF0000u), acc[3]);
        acc[4] = fmaf(wt, __uint_as_float(hv.z << 16),         acc[4]);
        acc[5] = fmaf(wt, __uint_as_float(hv.z & 0xFFFF0000u), acc[5]);
        acc[6] = fmaf(wt, __uint_as_float(hv.w << 16),         acc[6]);
        acc[7] = fmaf(wt, __uint_as_float(hv.w & 0xFFFF0000u), acc[7]);
      }
#pragma unroll
      for (int j = 0; j < 8; ++j) {
        float v = acc[j];
        s_hf[0][mg * FSTR_ + cg * 8 + j] = v;
        __hip_bfloat16 hi = __float2bfloat16(v);
        sh_h[0][mg * HSTR_ + cg * 8 + j] = hi;
        sh_l[0][mg * HSTR_ + cg * 8 + j] = __float2bfloat16(v - __bfloat162float(hi));
      }
    }
    __syncthreads();

    // P3: decoder GRU: gh = ctx @ dWhh^T (MFMA, split); gi = prev*dWih + b
    {
      bf16x8 ah[8], al[8];
#pragma unroll
      for (int kk = 0; kk < 8; ++kk) {
        ah[kk] = *(const bf16x8*)&sh_h[0][l16 * HSTR_ + kk * 32 + quad * 8];
        al[kk] = *(const bf16x8*)&sh_l[0][l16 * HSTR_ + kk * 32 + quad * 8];
      }
#pragma unroll
      for (int s2 = 0; s2 < 2; ++s2) {
        const int c = 2 * wid + s2;
        const int g = 16 * c + l16;
        const __hip_bfloat16* pr = dWhhB + (size_t)g * H_ + quad * 8;
        const __hip_bfloat16* pz = dWhhB + (size_t)(H_ + g) * H_ + quad * 8;
        const __hip_bfloat16* pn = dWhhB + (size_t)(2 * H_ + g) * H_ + quad * 8;
        f32x4 ar = {0.f, 0.f, 0.f, 0.f}, az = ar, anh = ar;
#pragma unroll
        for (int kk = 0; kk < 8; ++kk) {
          bf16x8 br = *(const bf16x8*)(pr + kk * 32);
          bf16x8 bz = *(const bf16x8*)(pz + kk * 32);
          bf16x8 bn = *(const bf16x8*)(pn + kk * 32);
          ar  = mfma16(al[kk], br, ar);  ar  = mfma16(ah[kk], br, ar);
          az  = mfma16(al[kk], bz, az);  az  = mfma16(ah[kk], bz, az);
          anh = mfma16(al[kk], bn, anh); anh = mfma16(ah[kk], bn, anh);
        }
        const float dr = s_dbr[g], dz = s_dbz[g], din = s_dbin[g], dhn = s_dbhn[g];
        const float wir = s_dwih[g], wiz = s_dwih[H_ + g], win = s_dwih[2 * H_ + g];
#pragma unroll
        for (int i = 0; i < 4; ++i) {
          const int m = quad * 4 + i;
          const float pv = s_prev[m];
          float r = sigm_(ar[i] + pv * wir + dr);
          float z = sigm_(az[i] + pv * wiz + dz);
          float n = tanh_(pv * win + din + r * (anh[i] + dhn));
          float ctxv = s_hf[0][m * FSTR_ + g];
          float hd = (1.0f - z) * n + z * ctxv;
          __hip_bfloat16 hi = __float2bfloat16(hd);
          sh_h[1][m * HSTR_ + g] = hi;
          sh_l[1][m * HSTR_ + g] = __float2bfloat16(hd - __bfloat162float(hi));
        }
      }
    }
    __syncthreads();

    // P4: fc1 + relu (MFMA, split) -> fp32 in s_scr
    {
      bf16x8 ad[8], adl[8];
#pragma unroll
      for (int kk = 0; kk < 8; ++kk) {
        ad[kk]  = *(const bf16x8*)&sh_h[1][l16 * HSTR_ + kk * 32 + quad * 8];
        adl[kk] = *(const bf16x8*)&sh_l[1][l16 * HSTR_ + kk * 32 + quad * 8];
      }
#pragma unroll
      for (int s2 = 0; s2 < 2; ++s2) {
        const int c = 2 * wid + s2;
        const int j = 16 * c + l16;
        const __hip_bfloat16* pw = f1WB + (size_t)j * H_ + quad * 8;
        f32x4 a1 = {0.f, 0.f, 0.f, 0.f};
#pragma unroll
        for (int kk = 0; kk < 8; ++kk) {
          bf16x8 bw = *(const bf16x8*)(pw + kk * 32);
          a1 = mfma16(adl[kk], bw, a1);
          a1 = mfma16(ad[kk],  bw, a1);
        }
        const float bj = s_f1b[j];
#pragma unroll
        for (int i = 0; i < 4; ++i) {
          const int m = quad * 4 + i;
          s_scr[m * SSTR_ + j] = fmaxf(a1[i] + bj, 0.0f);
        }
      }
    }
    __syncthreads();

    // P5: fc2 (fp32 dot) -> out, update prev
    {
      const float* ap = &s_scr[mg * SSTR_ + cg * 8];
      float p = 0.f;
#pragma unroll
      for (int j = 0; j < 8; ++j)
        p += ap[j] * s_f2w[cg * 8 + j];
#pragma unroll
      for (int off = 16; off >= 1; off >>= 1) p += __shfl_xor(p, off, 64);
      if (cg == 0) {
        float o = p + s_f2b;
        s_prev[mg] = o;
        dout[(size_t)(b0 + mg) * OUT_ + s] = o;
      }
    }
    __syncthreads();
  }
}

extern "C" void kernel_launch(void* const* d_in, const int* in_sizes, int n_in,
                              void* d_out, int out_size, void* d_ws, size_t ws_size,
                              hipStream_t stream) {
  (void)in_sizes; (void)n_in; (void)out_size; (void)ws_size;
  const float* x    = (const float*)d_in[0];
  const float* h0   = (const float*)d_in[1];
  const float* eWih = (const float*)d_in[2];
  const float* eWhh = (const float*)d_in[3];
  const float* ebih = (const float*)d_in[4];
  const float* ebhh = (const float*)d_in[5];
  const float* dWih = (const float*)d_in[6];
  const float* dWhh = (const float*)d_in[7];
  const float* dbih = (const float*)d_in[8];
  const float* dbhh = (const float*)d_in[9];
  const float* aWq  = (const float*)d_in[10];
  const float* abq  = (const float*)d_in[11];
  const float* f1W  = (const float*)d_in[12];
  const float* f1b  = (const float*)d_in[13];
  const float* f2W  = (const float*)d_in[14];
  const float* f2b  = (const float*)d_in[15];

  __hip_bfloat16* hs = (__hip_bfloat16*)d_ws;   // 134,217,728 B
  __hip_bfloat16* wb = (__hip_bfloat16*)((char*)d_ws + (size_t)B_ * T_ * H_ * 2);

  hipLaunchKernelGGL(af_convert_weights, dim3(256), dim3(256), 0, stream,
                     eWih, eWhh, dWhh, f1W, wb);
  hipLaunchKernelGGL(af_fused_kernel, dim3(NB_), dim3(NTH_), 0, stream,
                     x, h0, ebih, ebhh, dWih, dbih, dbhh, aWq, abq, f1b, f2W, f2b,
                     wb + W_EIH_, wb + W_EHH_, wb + W_DHH_, wb + W_F1_,
                     hs, (float*)d_out);
}